// Round 3
// baseline (677.804 us; speedup 1.0000x reference)
//
#include <hip/hip_runtime.h>
#include <hip/hip_bf16.h>
#include <cstdint>

// Problem dims
#define N_TOK 8192   // B*T
#define D_IN  1024
#define DFF   4096
#define NE    8
#define DEPTH 3      // gemm2 K-loop pipeline depth (LDS buffers)
#define MAXT256 40   // max 256-row tiles: 8192/256 + 8

typedef __bf16 bf16x8 __attribute__((ext_vector_type(8)));
typedef float  f32x4  __attribute__((ext_vector_type(4)));

// ---------- helpers ----------
__device__ __forceinline__ unsigned short f2bf(float f) {
  unsigned u = __float_as_uint(f);
  u += 0x7fffu + ((u >> 16) & 1u);   // RNE
  return (unsigned short)(u >> 16);
}

__device__ __forceinline__ void gll16(const void* g, void* l) {
  __builtin_amdgcn_global_load_lds(
      (__attribute__((address_space(1))) void*)g,
      (__attribute__((address_space(3))) void*)l, 16, 0, 0);
}

// ---------- gate: logits (fp64 acc) -> argmax -> top1; also x->bf16 ----------
__global__ __launch_bounds__(256) void gate_kernel(
    const float* __restrict__ x, const float* __restrict__ gW,
    const float* __restrict__ gb, unsigned short* __restrict__ xbf,
    int* __restrict__ top1) {
  int wave = threadIdx.x >> 6, lane = threadIdx.x & 63;
  int n = blockIdx.x * 4 + wave;
  const float* xr = x + (size_t)n * D_IN;
  double acc[NE];
#pragma unroll
  for (int e = 0; e < NE; ++e) acc[e] = 0.0;
#pragma unroll
  for (int j = 0; j < 16; ++j) {
    int d = j * 64 + lane;
    float v = xr[d];
    xbf[(size_t)n * D_IN + d] = f2bf(v);
    float4 g0 = *(const float4*)(gW + (size_t)d * 8);
    float4 g1 = *(const float4*)(gW + (size_t)d * 8 + 4);
    acc[0] += (double)v * (double)g0.x;
    acc[1] += (double)v * (double)g0.y;
    acc[2] += (double)v * (double)g0.z;
    acc[3] += (double)v * (double)g0.w;
    acc[4] += (double)v * (double)g1.x;
    acc[5] += (double)v * (double)g1.y;
    acc[6] += (double)v * (double)g1.z;
    acc[7] += (double)v * (double)g1.w;
  }
#pragma unroll
  for (int m = 32; m >= 1; m >>= 1) {
#pragma unroll
    for (int e = 0; e < NE; ++e) acc[e] += __shfl_xor(acc[e], m);
  }
  if (lane == 0) {
    float best = (float)acc[0] + gb[0];
    int be = 0;
#pragma unroll
    for (int e = 1; e < NE; ++e) {
      float lv = (float)acc[e] + gb[e];
      if (lv > best) { best = lv; be = e; }   // strict > => first max (jnp.argmax)
    }
    top1[n] = be;
  }
}

// ---------- build: counts/perm/worklists (128-tile list for gemm2, 256-tile list for gemm1) ----------
__global__ __launch_bounds__(1024) void build_kernel(
    const int* __restrict__ top1, int* __restrict__ hdr, int* __restrict__ perm,
    int* __restrict__ tile_e, int* __restrict__ tile_m, int* __restrict__ sub0,
    int* __restrict__ t256_e, int* __restrict__ t256_m, int* __restrict__ t256_s) {
  __shared__ int cnt[NE];
  int tid = threadIdx.x;
  if (tid < NE) cnt[tid] = 0;
  __syncthreads();
  int mye[8], myp[8];
#pragma unroll
  for (int r = 0; r < 8; ++r) {
    int n = r * 1024 + tid;
    int e = top1[n];
    mye[r] = e;
    myp[r] = atomicAdd(&cnt[e], 1);   // expert-local position
  }
  __syncthreads();
  if (tid == 0) {
    int o = 0;
    int n1 = 0, n2 = 0, n256 = 0;
    for (int e = 0; e < NE; ++e) {
      int Me = cnt[e];
      hdr[e] = Me;
      hdr[8 + e] = o;
      o += Me;
    }
    hdr[16] = o;
    for (int e = 0; e < NE; ++e) {
      int Me = cnt[e];
      int base2 = n2;
      n2 += (Me + 63) >> 6;
      for (int m0 = 0; m0 < Me; m0 += 128) {
        tile_e[n1] = e; tile_m[n1] = m0; sub0[n1] = base2 + (m0 >> 6); ++n1;
      }
      for (int m0 = 0; m0 < Me; m0 += 256) {
        t256_e[n256] = e; t256_m[n256] = m0; t256_s[n256] = base2 + (m0 >> 6); ++n256;
      }
    }
    hdr[17] = n1;
    hdr[18] = n2;
    hdr[19] = n256;
  }
  __syncthreads();
#pragma unroll
  for (int r = 0; r < 8; ++r) {
    int n = r * 1024 + tid;
    perm[mye[r] * N_TOK + myp[r]] = n;
  }
}

// ---------- A pack (256-tile, BK=32): [ti][kt 0..31][h 0..1][g 0..7][lane*16] ----------
// content: row = m0 + h*128 + g*16 + (lane&15); k = kt*32 + (lane>>4)*8 .. +8
__global__ __launch_bounds__(256) void apack256_kernel(
    const unsigned short* __restrict__ xbf, const int* __restrict__ hdr,
    const int* __restrict__ t256_e, const int* __restrict__ t256_m,
    const int* __restrict__ perm, unsigned short* __restrict__ Apack) {
  int ti = blockIdx.x >> 3;
  if (ti >= hdr[19]) return;
  int part = blockIdx.x & 7;
  int h = part >> 2, ktq = part & 3;     // ktq covers kt = ktq*8 .. +8
  int e = t256_e[ti], m0 = t256_m[ti], Me = hdr[e];
  int w = threadIdx.x >> 6, lane = threadIdx.x & 63;
  int kq = lane >> 4, m = lane & 15;
#pragma unroll
  for (int g2 = 0; g2 < 2; ++g2) {
    int g = w * 2 + g2;
    int r = m0 + h * 128 + g * 16 + m;
    if (r >= Me) r = Me - 1;
    int token = perm[e * N_TOK + r];
    const char* src = (const char*)xbf + (size_t)token * 2048 + kq * 16;
    char* dst = (char*)Apack + (size_t)ti * 524288 + h * 8192 + g * 1024 + lane * 16;
#pragma unroll
    for (int kt2 = 0; kt2 < 8; ++kt2) {
      int kt = ktq * 8 + kt2;
      *(int4*)(dst + (size_t)kt * 16384) = *(const int4*)(src + kt * 64);
    }
  }
}

// ---------- W1 pack: Bpack1 layout [e*16+nt][kt 0..31][h][g][ (kq*16+m)*16 ] ----------
__device__ __forceinline__ void wpack_w1_body(
    const float* __restrict__ src, unsigned short* __restrict__ dst, int bid) {
  __shared__ unsigned short tile[64][72];
  int e = bid >> 10;          // 16*64 tiles per expert
  int t = bid & 1023;
  int r0 = (t >> 6) * 64, c0 = (t & 63) * 64;   // r0: k base, c0: f base
  const float* s = src + (size_t)e * D_IN * DFF;
  int tr = threadIdx.x >> 4, tc = (threadIdx.x & 15) * 4;
#pragma unroll
  for (int p = 0; p < 4; ++p) {
    int row = r0 + tr + p * 16;  // k
    const float4 v = *(const float4*)(s + (size_t)row * DFF + c0 + tc);
    tile[tc + 0][tr + p * 16] = f2bf(v.x);
    tile[tc + 1][tr + p * 16] = f2bf(v.y);
    tile[tc + 2][tr + p * 16] = f2bf(v.z);
    tile[tc + 3][tr + p * 16] = f2bf(v.w);
  }
  __syncthreads();
#pragma unroll
  for (int u = 0; u < 2; ++u) {
    int c = u * 256 + threadIdx.x;        // 0..511 chunks of 16B
    int kk_l = c >> 8, gg_l = (c >> 6) & 3, kq = (c >> 4) & 3, mm = c & 15;
    int fl = gg_l * 16 + mm;
    int kl = kk_l * 32 + kq * 8;
    int4 val = *(const int4*)&tile[fl][kl];
    int f = c0 + fl;
    int nt = f >> 8, h = (f >> 7) & 1, g = (f >> 4) & 7;
    int kt = (r0 >> 5) + kk_l;            // 32-element K step index
    size_t off = ((size_t)(e * 16 + nt) * 32 + kt) * 16384 +
                 (size_t)h * 8192 + g * 1024 + (kq * 16 + mm) * 16;
    *(int4*)((char*)dst + off) = val;
  }
}

// ---------- W2 pack (unchanged gemm2 layout) ----------
__device__ __forceinline__ void wpack_body(
    const float* __restrict__ src, unsigned short* __restrict__ dst,
    int R, int C, int tiles_r, int tiles_c, int bid) {
  __shared__ unsigned short tile[64][72];
  int tpe = tiles_r * tiles_c;
  int e = bid / tpe;
  int t = bid % tpe;
  int r0 = (t / tiles_c) * 64, c0 = (t % tiles_c) * 64;
  const float* s = src + (size_t)e * R * C;
  int tr = threadIdx.x >> 4, tc = (threadIdx.x & 15) * 4;
#pragma unroll
  for (int p = 0; p < 4; ++p) {
    int row = r0 + tr + p * 16;
    const float4 v = *(const float4*)(s + (size_t)row * C + c0 + tc);
    tile[tc + 0][tr + p * 16] = f2bf(v.x);
    tile[tc + 1][tr + p * 16] = f2bf(v.y);
    tile[tc + 2][tr + p * 16] = f2bf(v.z);
    tile[tc + 3][tr + p * 16] = f2bf(v.w);
  }
  __syncthreads();
  int nkk = R >> 5, ntc = C >> 7;
#pragma unroll
  for (int u = 0; u < 2; ++u) {
    int c = u * 256 + threadIdx.x;
    int kk_l = c >> 8, gg_l = (c >> 6) & 3, kq = (c >> 4) & 3, mm = c & 15;
    int fl = gg_l * 16 + mm;
    int kl = kk_l * 32 + kq * 8;
    int4 val = *(const int4*)&tile[fl][kl];
    int f = c0 + fl;
    int nt = f >> 7, gg = (f >> 4) & 7;
    int kk = (r0 >> 5) + kk_l;
    size_t off = ((((size_t)e * ntc + nt) * nkk + kk) * 8 + gg) * 1024 + (kq * 16 + mm) * 16;
    *(int4*)((char*)dst + off) = val;
  }
}

__global__ __launch_bounds__(256) void wpack_both(
    const float* __restrict__ W1, unsigned short* __restrict__ B1,
    const float* __restrict__ W2, unsigned short* __restrict__ B2) {
  if (blockIdx.x < NE * 16 * 64)
    wpack_w1_body(W1, B1, blockIdx.x);
  else
    wpack_body(W2, B2, DFF, D_IN, 64, 16, blockIdx.x - NE * 16 * 64);
}

// ---------- GEMM1: 256x256 tile, BK=32, 8 waves, proven-cadence loop, counted vmcnt ----------
// LDS 64KB static: A dbuf [b][h][g][lane*16] @0..32768, B dbuf @32768..65536
__global__ __launch_bounds__(512, 2) void gemm1_256(
    const unsigned short* __restrict__ Apack, const unsigned short* __restrict__ Bpack1,
    const float* __restrict__ b1, const int* __restrict__ hdr,
    const int* __restrict__ t256_e, const int* __restrict__ t256_m,
    const int* __restrict__ t256_s, unsigned short* __restrict__ Hpack) {
  int ti = blockIdx.x >> 4;
  if (ti >= hdr[19]) return;
  int nt = blockIdx.x & 15;
  int e = t256_e[ti], m0 = t256_m[ti], Me = hdr[e];
  int n0 = nt * 256;

  __shared__ __align__(16) char smem[65536];

  int tid = threadIdx.x, wave = tid >> 6, lane = tid & 63;
  int wm = wave >> 2, wn = wave & 3;   // wave rows [wm*128,+128), cols [wn*64,+64)

  const char* aBase = (const char*)Apack + (size_t)ti * 524288;
  const char* bBase = (const char*)Bpack1 + (size_t)(e * 16 + nt) * 524288;

  // stage K-step kt into buffer kt&1: 4 gll16 per wave (B h0, B h1, A h0, A h1)
  auto stage = [&](int kt) {
    int b = kt & 1;
    const char* sB = bBase + (size_t)kt * 16384 + tid * 16;
    char* dB = smem + 32768 + b * 16384 + tid * 16;
    gll16(sB, dB);
    gll16(sB + 8192, dB + 8192);
    const char* sA = aBase + (size_t)kt * 16384 + tid * 16;
    char* dA = smem + b * 16384 + tid * 16;
    gll16(sA, dA);
    gll16(sA + 8192, dA + 8192);
  };

  // prologue: tiles 0,1 (8 vm ops/wave in flight)
  stage(0);
  stage(1);

  f32x4 acc[8][4];
#pragma unroll
  for (int i = 0; i < 8; ++i)
#pragma unroll
    for (int j = 0; j < 4; ++j) { f32x4 z = {0.f, 0.f, 0.f, 0.f}; acc[i][j] = z; }

  const int NITER = D_IN / 32;  // 32
  for (int T = 0; T < NITER; ++T) {
    int b = T & 1;
    // gate: all but the newest batch (4 ops, tile T+1) complete => tile T resident
    asm volatile("s_waitcnt vmcnt(4)" ::: "memory");
    __builtin_amdgcn_s_barrier();
    const char* Ap = smem + b * 16384 + wm * 8192 + lane * 16;
    const char* Bp = smem + 32768 + b * 16384 + (wn >> 1) * 8192 + (wn & 1) * 4096 + lane * 16;
    bf16x8 a[8], bf[4];
#pragma unroll
    for (int i = 0; i < 8; ++i) a[i] = *(const bf16x8*)(Ap + i * 1024);
#pragma unroll
    for (int j = 0; j < 4; ++j) bf[j] = *(const bf16x8*)(Bp + j * 1024);
    asm volatile("s_waitcnt lgkmcnt(0)" ::: "memory");
    __builtin_amdgcn_sched_barrier(0);
    __builtin_amdgcn_s_barrier();          // all waves done reading buffer b
    int nx = T + 2;
    if (nx > NITER - 1) nx = NITER - 1;    // redundant same-data restage near end (proven trick)
    stage(nx);                              // writes buffer (T+2)&1 = b (just freed)
    __builtin_amdgcn_s_setprio(1);
#pragma unroll
    for (int i = 0; i < 8; ++i)
#pragma unroll
      for (int j = 0; j < 4; ++j)
        acc[i][j] = __builtin_amdgcn_mfma_f32_16x16x32_bf16(a[i], bf[j], acc[i][j], 0, 0, 0);
    __builtin_amdgcn_s_setprio(0);
  }

  // ---- epilogue: gelu+bias -> Hpack via two 128-row passes through 64KB LDS ----
  asm volatile("s_waitcnt vmcnt(0)" ::: "memory");
  __syncthreads();
  unsigned short* Cl = (unsigned short*)smem;   // 128 x 256 bf16 = 64 KB
  int quad = lane >> 4, col_l = lane & 15;
  float bb[4];
#pragma unroll
  for (int j = 0; j < 4; ++j)
    bb[j] = b1[(size_t)e * DFF + n0 + wn * 64 + j * 16 + col_l];
  int s0 = t256_s[ti];
  int rem = Me - m0; if (rem > 256) rem = 256;
  int nsv = (rem + 63) >> 6;     // valid 64-row subtiles (1..4)
#pragma unroll
  for (int h = 0; h < 2; ++h) {
    if (wm == h) {
#pragma unroll
      for (int i = 0; i < 8; ++i) {
#pragma unroll
        for (int j = 0; j < 4; ++j) {
          int lc = wn * 64 + j * 16 + col_l;
#pragma unroll
          for (int r = 0; r < 4; ++r) {
            int lr_l = i * 16 + quad * 4 + r;
            float v = acc[i][j][r] + bb[j];
            v = 0.5f * v * (1.0f + erff(v * 0.70710678118654752f));  // exact gelu
            Cl[lr_l * 256 + lc] = f2bf(v);
          }
        }
      }
    }
    __syncthreads();
#pragma unroll
    for (int u = 0; u < 8; ++u) {
      int c = u * 512 + tid;       // 0..4095 chunks of 16B
      int lr_l = c >> 5, fc = c & 31;
      int lr = h * 128 + lr_l;
      int sv = lr >> 6;
      if (sv < nsv) {
        int4 val = *(const int4*)(Cl + lr_l * 256 + fc * 8);
        int wi2 = s0 + sv;
        int m2 = lr & 63;
        int gg = m2 >> 4, mm = m2 & 15;
        int kk2 = nt * 8 + (fc >> 2), kq2 = fc & 3;
        *(int4*)((char*)Hpack + ((size_t)wi2 * 128 + kk2) * 4096 + gg * 1024 + (kq2 * 16 + mm) * 16) = val;
      }
    }
    __syncthreads();
  }
}

// ---------- GEMM2: out[token] = Hpack @ W2 + b2, BM=128, pipelined (unchanged) ----------
__global__ __launch_bounds__(256) void gemm2(
    const unsigned short* __restrict__ Hpack, const unsigned short* __restrict__ Bpack2,
    const float* __restrict__ b2, const int* __restrict__ hdr,
    const int* __restrict__ tile_e, const int* __restrict__ tile_m,
    const int* __restrict__ sub0, const int* __restrict__ perm,
    float* __restrict__ out) {
  int wi = blockIdx.x >> 3;
  if (wi >= hdr[17]) return;
  int nt = blockIdx.x & 7;
  int e = tile_e[wi];
  int m0 = tile_m[wi];
  int Me = hdr[e];
  int n0 = nt * 128;
  int s0 = sub0[wi];
  int s1 = (m0 + 64 < Me) ? s0 + 1 : s0;

  __shared__ __align__(16) char smem[49152];
  char* Asm = smem;
  char* Bsm = smem + 24576;

  int tid = threadIdx.x, wave = tid >> 6, lane = tid & 63;
  int wm = wave >> 1, wn = wave & 1;

  const char* abase_s[2];
  int agl[2];
  int off_s[2];
#pragma unroll
  for (int s = 0; s < 2; ++s) {
    int g = wave * 2 + s;
    int sv = g >> 2;
    abase_s[s] = (const char*)Hpack + (size_t)((sv ? s1 : s0) * 128) * 4096;
    agl[s] = (g & 3) * 1024 + lane * 16;
    off_s[s] = g * 1024 + lane * 16;
  }
  const char* bbase = (const char*)Bpack2 + (size_t)(e * 8 + nt) * 128 * 8192;

  const int NITER = DFF / 32;  // 128
#pragma unroll
  for (int p = 0; p < DEPTH; ++p) {
    gll16(abase_s[0] + (size_t)p * 4096 + agl[0], Asm + p * 8192 + off_s[0]);
    gll16(abase_s[1] + (size_t)p * 4096 + agl[1], Asm + p * 8192 + off_s[1]);
    gll16(bbase + (size_t)p * 8192 + off_s[0], Bsm + p * 8192 + off_s[0]);
    gll16(bbase + (size_t)p * 8192 + off_s[1], Bsm + p * 8192 + off_s[1]);
  }

  f32x4 acc[4][4];
#pragma unroll
  for (int i = 0; i < 4; ++i)
#pragma unroll
    for (int j = 0; j < 4; ++j) { f32x4 z = {0.f, 0.f, 0.f, 0.f}; acc[i][j] = z; }

  int cur = 0;
  for (int kk = 0; kk < NITER; ++kk) {
    asm volatile("s_waitcnt vmcnt(8)" ::: "memory");
    __builtin_amdgcn_s_barrier();
    const char* ab = Asm + cur * 8192;
    const char* bb = Bsm + cur * 8192;
    bf16x8 af[4], bfv[4];
#pragma unroll
    for (int i = 0; i < 4; ++i)
      af[i] = *(const bf16x8*)(ab + (wm * 4 + i) * 1024 + lane * 16);
#pragma unroll
    for (int j = 0; j < 4; ++j)
      bfv[j] = *(const bf16x8*)(bb + (wn * 4 + j) * 1024 + lane * 16);
    asm volatile("s_waitcnt lgkmcnt(0)" ::: "memory");
    __builtin_amdgcn_s_barrier();
    int nx = kk + DEPTH;
    if (nx > NITER - 1) nx = NITER - 1;
    char* ad = Asm + cur * 8192;
    char* bd = Bsm + cur * 8192;
    gll16(abase_s[0] + (size_t)nx * 4096 + agl[0], ad + off_s[0]);
    gll16(abase_s[1] + (size_t)nx * 4096 + agl[1], ad + off_s[1]);
    gll16(bbase + (size_t)nx * 8192 + off_s[0], bd + off_s[0]);
    gll16(bbase + (size_t)nx * 8192 + off_s[1], bd + off_s[1]);
#pragma unroll
    for (int i = 0; i < 4; ++i)
#pragma unroll
      for (int j = 0; j < 4; ++j)
        acc[i][j] = __builtin_amdgcn_mfma_f32_16x16x32_bf16(af[i], bfv[j], acc[i][j], 0, 0, 0);
    cur = (cur == DEPTH - 1) ? 0 : cur + 1;
  }

  int quad = lane >> 4, col_l = lane & 15;
#pragma unroll
  for (int i = 0; i < 4; ++i) {
    int rbase = m0 + wm * 64 + i * 16 + quad * 4;
#pragma unroll
    for (int j = 0; j < 4; ++j) {
      int col = n0 + wn * 64 + j * 16 + col_l;
      float bb = b2[(size_t)e * D_IN + col];
#pragma unroll
      for (int r = 0; r < 4; ++r) {
        int rr = rbase + r;
        if (rr < Me) {
          int token = perm[e * N_TOK + rr];
          out[(size_t)token * D_IN + col] = acc[i][j][r] + bb;
        }
      }
    }
  }
}

// ---------- launch ----------
extern "C" void kernel_launch(void* const* d_in, const int* in_sizes, int n_in,
                              void* d_out, int out_size, void* d_ws, size_t ws_size,
                              hipStream_t stream) {
  const float* x  = (const float*)d_in[0];
  const float* gW = (const float*)d_in[1];
  const float* gb = (const float*)d_in[2];
  const float* W1 = (const float*)d_in[3];
  const float* b1 = (const float*)d_in[4];
  const float* W2 = (const float*)d_in[5];
  const float* b2 = (const float*)d_in[6];
  float* out = (float*)d_out;

  char* ws = (char*)d_ws;
  int* hdr     = (int*)ws;                 // counts[8], offsets[9], nt1, nt2, nt256
  int* tile_e  = (int*)(ws + 4096);
  int* tile_m  = (int*)(ws + 4608);
  int* sub0    = (int*)(ws + 5120);
  int* t256_e  = (int*)(ws + 5632);
  int* t256_m  = (int*)(ws + 6144);
  int* t256_s  = (int*)(ws + 6656);
  int* top1    = (int*)(ws + 8192);                       // 32 KB
  int* perm    = (int*)(ws + 65536);                      // 256 KB
  unsigned short* xbf    = (unsigned short*)(ws + 524288);    // 16 MB (dead after apack)
  unsigned short* Bpack2 = (unsigned short*)(ws + 524288);    // 64 MB overlay; written after apack
  unsigned short* Apack  = (unsigned short*)(ws + 69206016);  // 20.5 MB (40 x 512 KB)
  unsigned short* Bpack1 = (unsigned short*)(ws + 92274688);  // 64 MB (128 x 512 KB)
  unsigned short* Hpack  = (unsigned short*)(ws + 159383552); // 70.8 MB

  gate_kernel<<<N_TOK / 4, 256, 0, stream>>>(x, gW, gb, xbf, top1);
  build_kernel<<<1, 1024, 0, stream>>>(top1, hdr, perm, tile_e, tile_m, sub0,
                                       t256_e, t256_m, t256_s);
  apack256_kernel<<<MAXT256 * 8, 256, 0, stream>>>(xbf, hdr, t256_e, t256_m, perm, Apack);
  wpack_both<<<NE * 16 * 64 + NE * 64 * 16, 256, 0, stream>>>(W1, Bpack1, W2, Bpack2);
  gemm1_256<<<MAXT256 * 16, 512, 0, stream>>>(Apack, Bpack1, b1, hdr,
                                              t256_e, t256_m, t256_s, Hpack);
  gemm2<<<71 * 8, 256, 0, stream>>>(Hpack, Bpack2, b2, hdr, tile_e, tile_m, sub0, perm, out);
}

// Round 6
// 673.636 us; speedup vs baseline: 1.0062x; 1.0062x over previous
//
#include <hip/hip_runtime.h>
#include <hip/hip_bf16.h>
#include <cstdint>

// Problem dims
#define N_TOK 8192   // B*T
#define D_IN  1024
#define DFF   4096
#define NE    8
#define DEPTH 3      // gemm2 K-loop pipeline depth (LDS buffers)
#define MAXT256 40   // max 256-row tiles: 8192/256 + 8

typedef __bf16 bf16x8 __attribute__((ext_vector_type(8)));
typedef float  f32x4  __attribute__((ext_vector_type(4)));

// ---------- helpers ----------
__device__ __forceinline__ unsigned short f2bf(float f) {
  unsigned u = __float_as_uint(f);
  u += 0x7fffu + ((u >> 16) & 1u);   // RNE
  return (unsigned short)(u >> 16);
}

__device__ __forceinline__ void gll16(const void* g, void* l) {
  __builtin_amdgcn_global_load_lds(
      (__attribute__((address_space(1))) void*)g,
      (__attribute__((address_space(3))) void*)l, 16, 0, 0);
}

// ---------- gate: logits (fp64 acc) -> argmax -> top1; also x->bf16 ----------
__global__ __launch_bounds__(256) void gate_kernel(
    const float* __restrict__ x, const float* __restrict__ gW,
    const float* __restrict__ gb, unsigned short* __restrict__ xbf,
    int* __restrict__ top1) {
  int wave = threadIdx.x >> 6, lane = threadIdx.x & 63;
  int n = blockIdx.x * 4 + wave;
  const float* xr = x + (size_t)n * D_IN;
  double acc[NE];
#pragma unroll
  for (int e = 0; e < NE; ++e) acc[e] = 0.0;
#pragma unroll
  for (int j = 0; j < 16; ++j) {
    int d = j * 64 + lane;
    float v = xr[d];
    xbf[(size_t)n * D_IN + d] = f2bf(v);
    float4 g0 = *(const float4*)(gW + (size_t)d * 8);
    float4 g1 = *(const float4*)(gW + (size_t)d * 8 + 4);
    acc[0] += (double)v * (double)g0.x;
    acc[1] += (double)v * (double)g0.y;
    acc[2] += (double)v * (double)g0.z;
    acc[3] += (double)v * (double)g0.w;
    acc[4] += (double)v * (double)g1.x;
    acc[5] += (double)v * (double)g1.y;
    acc[6] += (double)v * (double)g1.z;
    acc[7] += (double)v * (double)g1.w;
  }
#pragma unroll
  for (int m = 32; m >= 1; m >>= 1) {
#pragma unroll
    for (int e = 0; e < NE; ++e) acc[e] += __shfl_xor(acc[e], m);
  }
  if (lane == 0) {
    float best = (float)acc[0] + gb[0];
    int be = 0;
#pragma unroll
    for (int e = 1; e < NE; ++e) {
      float lv = (float)acc[e] + gb[e];
      if (lv > best) { best = lv; be = e; }   // strict > => first max (jnp.argmax)
    }
    top1[n] = be;
  }
}

// ---------- build: counts/perm/worklists (128-tile list for gemm2, 256-tile list for gemm1) ----------
__global__ __launch_bounds__(1024) void build_kernel(
    const int* __restrict__ top1, int* __restrict__ hdr, int* __restrict__ perm,
    int* __restrict__ tile_e, int* __restrict__ tile_m, int* __restrict__ sub0,
    int* __restrict__ t256_e, int* __restrict__ t256_m, int* __restrict__ t256_s) {
  __shared__ int cnt[NE];
  int tid = threadIdx.x;
  if (tid < NE) cnt[tid] = 0;
  __syncthreads();
  int mye[8], myp[8];
#pragma unroll
  for (int r = 0; r < 8; ++r) {
    int n = r * 1024 + tid;
    int e = top1[n];
    mye[r] = e;
    myp[r] = atomicAdd(&cnt[e], 1);   // expert-local position
  }
  __syncthreads();
  if (tid == 0) {
    int o = 0;
    int n1 = 0, n2 = 0, n256 = 0;
    for (int e = 0; e < NE; ++e) {
      int Me = cnt[e];
      hdr[e] = Me;
      hdr[8 + e] = o;
      o += Me;
    }
    hdr[16] = o;
    for (int e = 0; e < NE; ++e) {
      int Me = cnt[e];
      int base2 = n2;
      n2 += (Me + 63) >> 6;
      for (int m0 = 0; m0 < Me; m0 += 128) {
        tile_e[n1] = e; tile_m[n1] = m0; sub0[n1] = base2 + (m0 >> 6); ++n1;
      }
      for (int m0 = 0; m0 < Me; m0 += 256) {
        t256_e[n256] = e; t256_m[n256] = m0; t256_s[n256] = base2 + (m0 >> 6); ++n256;
      }
    }
    hdr[17] = n1;
    hdr[18] = n2;
    hdr[19] = n256;
  }
  __syncthreads();
#pragma unroll
  for (int r = 0; r < 8; ++r) {
    int n = r * 1024 + tid;
    perm[mye[r] * N_TOK + myp[r]] = n;
  }
}

// ---------- A pack (256-tile, BK=32): [ti][kt 0..31][h 0..1][g 0..7][lane*16] ----------
// content: row = m0 + h*128 + g*16 + (lane&15); k = kt*32 + (lane>>4)*8 .. +8
__global__ __launch_bounds__(256) void apack256_kernel(
    const unsigned short* __restrict__ xbf, const int* __restrict__ hdr,
    const int* __restrict__ t256_e, const int* __restrict__ t256_m,
    const int* __restrict__ perm, unsigned short* __restrict__ Apack) {
  int ti = blockIdx.x >> 3;
  if (ti >= hdr[19]) return;
  int part = blockIdx.x & 7;
  int h = part >> 2, ktq = part & 3;     // ktq covers kt = ktq*8 .. +8
  int e = t256_e[ti], m0 = t256_m[ti], Me = hdr[e];
  int w = threadIdx.x >> 6, lane = threadIdx.x & 63;
  int kq = lane >> 4, m = lane & 15;
#pragma unroll
  for (int g2 = 0; g2 < 2; ++g2) {
    int g = w * 2 + g2;
    int r = m0 + h * 128 + g * 16 + m;
    if (r >= Me) r = Me - 1;
    int token = perm[e * N_TOK + r];
    const char* src = (const char*)xbf + (size_t)token * 2048 + kq * 16;
    char* dst = (char*)Apack + (size_t)ti * 524288 + h * 8192 + g * 1024 + lane * 16;
#pragma unroll
    for (int kt2 = 0; kt2 < 8; ++kt2) {
      int kt = ktq * 8 + kt2;
      *(int4*)(dst + (size_t)kt * 16384) = *(const int4*)(src + kt * 64);
    }
  }
}

// ---------- W1 pack: Bpack1 layout [e*16+nt][kt 0..31][h][g][ (kq*16+m)*16 ] ----------
__device__ __forceinline__ void wpack_w1_body(
    const float* __restrict__ src, unsigned short* __restrict__ dst, int bid) {
  __shared__ unsigned short tile[64][72];
  int e = bid >> 10;          // 16*64 tiles per expert
  int t = bid & 1023;
  int r0 = (t >> 6) * 64, c0 = (t & 63) * 64;   // r0: k base, c0: f base
  const float* s = src + (size_t)e * D_IN * DFF;
  int tr = threadIdx.x >> 4, tc = (threadIdx.x & 15) * 4;
#pragma unroll
  for (int p = 0; p < 4; ++p) {
    int row = r0 + tr + p * 16;  // k
    const float4 v = *(const float4*)(s + (size_t)row * DFF + c0 + tc);
    tile[tc + 0][tr + p * 16] = f2bf(v.x);
    tile[tc + 1][tr + p * 16] = f2bf(v.y);
    tile[tc + 2][tr + p * 16] = f2bf(v.z);
    tile[tc + 3][tr + p * 16] = f2bf(v.w);
  }
  __syncthreads();
#pragma unroll
  for (int u = 0; u < 2; ++u) {
    int c = u * 256 + threadIdx.x;        // 0..511 chunks of 16B
    int kk_l = c >> 8, gg_l = (c >> 6) & 3, kq = (c >> 4) & 3, mm = c & 15;
    int fl = gg_l * 16 + mm;
    int kl = kk_l * 32 + kq * 8;
    int4 val = *(const int4*)&tile[fl][kl];
    int f = c0 + fl;
    int nt = f >> 8, h = (f >> 7) & 1, g = (f >> 4) & 7;
    int kt = (r0 >> 5) + kk_l;            // 32-element K step index
    size_t off = ((size_t)(e * 16 + nt) * 32 + kt) * 16384 +
                 (size_t)h * 8192 + g * 1024 + (kq * 16 + mm) * 16;
    *(int4*)((char*)dst + off) = val;
  }
}

// ---------- W2 pack (unchanged gemm2 layout) ----------
__device__ __forceinline__ void wpack_body(
    const float* __restrict__ src, unsigned short* __restrict__ dst,
    int R, int C, int tiles_r, int tiles_c, int bid) {
  __shared__ unsigned short tile[64][72];
  int tpe = tiles_r * tiles_c;
  int e = bid / tpe;
  int t = bid % tpe;
  int r0 = (t / tiles_c) * 64, c0 = (t % tiles_c) * 64;
  const float* s = src + (size_t)e * R * C;
  int tr = threadIdx.x >> 4, tc = (threadIdx.x & 15) * 4;
#pragma unroll
  for (int p = 0; p < 4; ++p) {
    int row = r0 + tr + p * 16;
    const float4 v = *(const float4*)(s + (size_t)row * C + c0 + tc);
    tile[tc + 0][tr + p * 16] = f2bf(v.x);
    tile[tc + 1][tr + p * 16] = f2bf(v.y);
    tile[tc + 2][tr + p * 16] = f2bf(v.z);
    tile[tc + 3][tr + p * 16] = f2bf(v.w);
  }
  __syncthreads();
  int nkk = R >> 5, ntc = C >> 7;
#pragma unroll
  for (int u = 0; u < 2; ++u) {
    int c = u * 256 + threadIdx.x;
    int kk_l = c >> 8, gg_l = (c >> 6) & 3, kq = (c >> 4) & 3, mm = c & 15;
    int fl = gg_l * 16 + mm;
    int kl = kk_l * 32 + kq * 8;
    int4 val = *(const int4*)&tile[fl][kl];
    int f = c0 + fl;
    int nt = f >> 7, gg = (f >> 4) & 7;
    int kk = (r0 >> 5) + kk_l;
    size_t off = ((((size_t)e * ntc + nt) * nkk + kk) * 8 + gg) * 1024 + (kq * 16 + mm) * 16;
    *(int4*)((char*)dst + off) = val;
  }
}

__global__ __launch_bounds__(256) void wpack_both(
    const float* __restrict__ W1, unsigned short* __restrict__ B1,
    const float* __restrict__ W2, unsigned short* __restrict__ B2) {
  if (blockIdx.x < NE * 16 * 64)
    wpack_w1_body(W1, B1, blockIdx.x);
  else
    wpack_body(W2, B2, DFF, D_IN, 64, 16, blockIdx.x - NE * 16 * 64);
}

// ---------- GEMM1: 256x256 tile, BK=32, 8 waves, DEPTH=3, ONE barrier per K-step ----------
// LDS 96KB dynamic: A 3x16KB @0, B 3x16KB @49152.
// Safety: stage(T+2) at iter T overwrites buf (T+2)%3, which holds tile T-1; all waves'
// reads of tile T-1 drained before the iter-T barrier (compiler waitcnts precede each
// consuming MFMA, MFMA cluster precedes barrier). Gate vmcnt(4): tile T staged at iter
// T-2 -> 2-iteration issue-to-wait distance covers HBM/L3 latency at 1 block/CU.
__global__ __launch_bounds__(512, 2) void gemm1_256(
    const unsigned short* __restrict__ Apack, const unsigned short* __restrict__ Bpack1,
    const float* __restrict__ b1, const int* __restrict__ hdr,
    const int* __restrict__ t256_e, const int* __restrict__ t256_m,
    const int* __restrict__ t256_s, unsigned short* __restrict__ Hpack) {
  int ti = blockIdx.x >> 4;
  if (ti >= hdr[19]) return;
  int nt = blockIdx.x & 15;
  int e = t256_e[ti], m0 = t256_m[ti], Me = hdr[e];
  int n0 = nt * 256;

  extern __shared__ __align__(16) char smem[];

  int tid = threadIdx.x, wave = tid >> 6, lane = tid & 63;
  int wm = wave >> 2, wn = wave & 3;   // wave rows [wm*128,+128), cols [wn*64,+64)

  const char* aBase = (const char*)Apack + (size_t)ti * 524288;
  const char* bBase = (const char*)Bpack1 + (size_t)(e * 16 + nt) * 524288;

  // stage K-step kt into buffer kt%3: 4 gll16 per wave (B lo, B hi, A lo, A hi)
  auto stage = [&](int kt) {
    int b = kt % 3;
    const char* sB = bBase + (size_t)kt * 16384 + tid * 16;
    char* dB = smem + 49152 + b * 16384 + tid * 16;
    gll16(sB, dB);
    gll16(sB + 8192, dB + 8192);
    const char* sA = aBase + (size_t)kt * 16384 + tid * 16;
    char* dA = smem + b * 16384 + tid * 16;
    gll16(sA, dA);
    gll16(sA + 8192, dA + 8192);
  };

  // prologue: tiles 0,1 in flight (8 vm ops/wave)
  stage(0);
  stage(1);

  f32x4 acc[8][4];
#pragma unroll
  for (int i = 0; i < 8; ++i)
#pragma unroll
    for (int j = 0; j < 4; ++j) { f32x4 z = {0.f, 0.f, 0.f, 0.f}; acc[i][j] = z; }

  const int NITER = D_IN / 32;  // 32
  for (int T = 0; T < NITER; ++T) {
    // gate: allow newest 4 (tile T+1) outstanding => tile T fully resident
    asm volatile("s_waitcnt vmcnt(4)" ::: "memory");
    __builtin_amdgcn_s_barrier();
    int nx = T + 2;
    if (nx > NITER - 1) nx = NITER - 1;  // tail: same-data restage (benign WAW, proven)
    stage(nx);                            // overwrites buf (T+2)%3 (= tile T-1, reads drained)
    int b = T % 3;
    const char* Ap = smem + b * 16384 + wm * 8192 + lane * 16;
    const char* Bp = smem + 49152 + b * 16384 + (wn >> 1) * 8192 + (wn & 1) * 4096 + lane * 16;
    bf16x8 a[8], bf[4];
#pragma unroll
    for (int i = 0; i < 8; ++i) a[i] = *(const bf16x8*)(Ap + i * 1024);
#pragma unroll
    for (int j = 0; j < 4; ++j) bf[j] = *(const bf16x8*)(Bp + j * 1024);
    // no lgkmcnt(0)/sched_barrier: compiler interleaves ds_reads with MFMAs (fine-grained waits)
#pragma unroll
    for (int i = 0; i < 8; ++i)
#pragma unroll
      for (int j = 0; j < 4; ++j)
        acc[i][j] = __builtin_amdgcn_mfma_f32_16x16x32_bf16(a[i], bf[j], acc[i][j], 0, 0, 0);
  }

  // ---- epilogue: gelu+bias -> Hpack via two 128-row passes through 64KB of LDS ----
  asm volatile("s_waitcnt vmcnt(0)" ::: "memory");
  __syncthreads();
  unsigned short* Cl = (unsigned short*)smem;   // 128 x 256 bf16 = 64 KB
  int quad = lane >> 4, col_l = lane & 15;
  float bb[4];
#pragma unroll
  for (int j = 0; j < 4; ++j)
    bb[j] = b1[(size_t)e * DFF + n0 + wn * 64 + j * 16 + col_l];
  int s0 = t256_s[ti];
  int rem = Me - m0; if (rem > 256) rem = 256;
  int nsv = (rem + 63) >> 6;     // valid 64-row subtiles (1..4)
#pragma unroll
  for (int h = 0; h < 2; ++h) {
    if (wm == h) {
#pragma unroll
      for (int i = 0; i < 8; ++i) {
#pragma unroll
        for (int j = 0; j < 4; ++j) {
          int lc = wn * 64 + j * 16 + col_l;
#pragma unroll
          for (int r = 0; r < 4; ++r) {
            int lr_l = i * 16 + quad * 4 + r;
            float v = acc[i][j][r] + bb[j];
            v = 0.5f * v * (1.0f + erff(v * 0.70710678118654752f));  // exact gelu
            Cl[lr_l * 256 + lc] = f2bf(v);
          }
        }
      }
    }
    __syncthreads();
#pragma unroll
    for (int u = 0; u < 8; ++u) {
      int c = u * 512 + tid;       // 0..4095 chunks of 16B
      int lr_l = c >> 5, fc = c & 31;
      int lr = h * 128 + lr_l;
      int sv = lr >> 6;
      if (sv < nsv) {
        int4 val = *(const int4*)(Cl + lr_l * 256 + fc * 8);
        int wi2 = s0 + sv;
        int m2 = lr & 63;
        int gg = m2 >> 4, mm = m2 & 15;
        int kk2 = nt * 8 + (fc >> 2), kq2 = fc & 3;
        *(int4*)((char*)Hpack + ((size_t)wi2 * 128 + kk2) * 4096 + gg * 1024 + (kq2 * 16 + mm) * 16) = val;
      }
    }
    __syncthreads();
  }
}

// ---------- GEMM2: out[token] = Hpack @ W2 + b2, BM=128, pipelined (unchanged) ----------
__global__ __launch_bounds__(256) void gemm2(
    const unsigned short* __restrict__ Hpack, const unsigned short* __restrict__ Bpack2,
    const float* __restrict__ b2, const int* __restrict__ hdr,
    const int* __restrict__ tile_e, const int* __restrict__ tile_m,
    const int* __restrict__ sub0, const int* __restrict__ perm,
    float* __restrict__ out) {
  int wi = blockIdx.x >> 3;
  if (wi >= hdr[17]) return;
  int nt = blockIdx.x & 7;
  int e = tile_e[wi];
  int m0 = tile_m[wi];
  int Me = hdr[e];
  int n0 = nt * 128;
  int s0 = sub0[wi];
  int s1 = (m0 + 64 < Me) ? s0 + 1 : s0;

  __shared__ __align__(16) char smem[49152];
  char* Asm = smem;
  char* Bsm = smem + 24576;

  int tid = threadIdx.x, wave = tid >> 6, lane = tid & 63;
  int wm = wave >> 1, wn = wave & 1;

  const char* abase_s[2];
  int agl[2];
  int off_s[2];
#pragma unroll
  for (int s = 0; s < 2; ++s) {
    int g = wave * 2 + s;
    int sv = g >> 2;
    abase_s[s] = (const char*)Hpack + (size_t)((sv ? s1 : s0) * 128) * 4096;
    agl[s] = (g & 3) * 1024 + lane * 16;
    off_s[s] = g * 1024 + lane * 16;
  }
  const char* bbase = (const char*)Bpack2 + (size_t)(e * 8 + nt) * 128 * 8192;

  const int NITER = DFF / 32;  // 128
#pragma unroll
  for (int p = 0; p < DEPTH; ++p) {
    gll16(abase_s[0] + (size_t)p * 4096 + agl[0], Asm + p * 8192 + off_s[0]);
    gll16(abase_s[1] + (size_t)p * 4096 + agl[1], Asm + p * 8192 + off_s[1]);
    gll16(bbase + (size_t)p * 8192 + off_s[0], Bsm + p * 8192 + off_s[0]);
    gll16(bbase + (size_t)p * 8192 + off_s[1], Bsm + p * 8192 + off_s[1]);
  }

  f32x4 acc[4][4];
#pragma unroll
  for (int i = 0; i < 4; ++i)
#pragma unroll
    for (int j = 0; j < 4; ++j) { f32x4 z = {0.f, 0.f, 0.f, 0.f}; acc[i][j] = z; }

  int cur = 0;
  for (int kk = 0; kk < NITER; ++kk) {
    asm volatile("s_waitcnt vmcnt(8)" ::: "memory");
    __builtin_amdgcn_s_barrier();
    const char* ab = Asm + cur * 8192;
    const char* bb = Bsm + cur * 8192;
    bf16x8 af[4], bfv[4];
#pragma unroll
    for (int i = 0; i < 4; ++i)
      af[i] = *(const bf16x8*)(ab + (wm * 4 + i) * 1024 + lane * 16);
#pragma unroll
    for (int j = 0; j < 4; ++j)
      bfv[j] = *(const bf16x8*)(bb + (wn * 4 + j) * 1024 + lane * 16);
    asm volatile("s_waitcnt lgkmcnt(0)" ::: "memory");
    __builtin_amdgcn_s_barrier();
    int nx = kk + DEPTH;
    if (nx > NITER - 1) nx = NITER - 1;
    char* ad = Asm + cur * 8192;
    char* bd = Bsm + cur * 8192;
    gll16(abase_s[0] + (size_t)nx * 4096 + agl[0], ad + off_s[0]);
    gll16(abase_s[1] + (size_t)nx * 4096 + agl[1], ad + off_s[1]);
    gll16(bbase + (size_t)nx * 8192 + off_s[0], bd + off_s[0]);
    gll16(bbase + (size_t)nx * 8192 + off_s[1], bd + off_s[1]);
#pragma unroll
    for (int i = 0; i < 4; ++i)
#pragma unroll
      for (int j = 0; j < 4; ++j)
        acc[i][j] = __builtin_amdgcn_mfma_f32_16x16x32_bf16(af[i], bfv[j], acc[i][j], 0, 0, 0);
    cur = (cur == DEPTH - 1) ? 0 : cur + 1;
  }

  int quad = lane >> 4, col_l = lane & 15;
#pragma unroll
  for (int i = 0; i < 4; ++i) {
    int rbase = m0 + wm * 64 + i * 16 + quad * 4;
#pragma unroll
    for (int j = 0; j < 4; ++j) {
      int col = n0 + wn * 64 + j * 16 + col_l;
      float bb = b2[(size_t)e * D_IN + col];
#pragma unroll
      for (int r = 0; r < 4; ++r) {
        int rr = rbase + r;
        if (rr < Me) {
          int token = perm[e * N_TOK + rr];
          out[(size_t)token * D_IN + col] = acc[i][j][r] + bb;
        }
      }
    }
  }
}

// ---------- launch ----------
extern "C" void kernel_launch(void* const* d_in, const int* in_sizes, int n_in,
                              void* d_out, int out_size, void* d_ws, size_t ws_size,
                              hipStream_t stream) {
  const float* x  = (const float*)d_in[0];
  const float* gW = (const float*)d_in[1];
  const float* gb = (const float*)d_in[2];
  const float* W1 = (const float*)d_in[3];
  const float* b1 = (const float*)d_in[4];
  const float* W2 = (const float*)d_in[5];
  const float* b2 = (const float*)d_in[6];
  float* out = (float*)d_out;

  char* ws = (char*)d_ws;
  int* hdr     = (int*)ws;                 // counts[8], offsets[9], nt1, nt2, nt256
  int* tile_e  = (int*)(ws + 4096);
  int* tile_m  = (int*)(ws + 4608);
  int* sub0    = (int*)(ws + 5120);
  int* t256_e  = (int*)(ws + 5632);
  int* t256_m  = (int*)(ws + 6144);
  int* t256_s  = (int*)(ws + 6656);
  int* top1    = (int*)(ws + 8192);                       // 32 KB
  int* perm    = (int*)(ws + 65536);                      // 256 KB
  unsigned short* xbf    = (unsigned short*)(ws + 524288);    // 16 MB (dead after apack)
  unsigned short* Bpack2 = (unsigned short*)(ws + 524288);    // 64 MB overlay; written after apack
  unsigned short* Apack  = (unsigned short*)(ws + 69206016);  // 20.5 MB (40 x 512 KB)
  unsigned short* Bpack1 = (unsigned short*)(ws + 92274688);  // 64 MB (128 x 512 KB)
  unsigned short* Hpack  = (unsigned short*)(ws + 159383552); // 70.8 MB

  (void)hipFuncSetAttribute((const void*)gemm1_256,
                            hipFuncAttributeMaxDynamicSharedMemorySize, 98304);

  gate_kernel<<<N_TOK / 4, 256, 0, stream>>>(x, gW, gb, xbf, top1);
  build_kernel<<<1, 1024, 0, stream>>>(top1, hdr, perm, tile_e, tile_m, sub0,
                                       t256_e, t256_m, t256_s);
  apack256_kernel<<<MAXT256 * 8, 256, 0, stream>>>(xbf, hdr, t256_e, t256_m, perm, Apack);
  wpack_both<<<NE * 16 * 64 + NE * 64 * 16, 256, 0, stream>>>(W1, Bpack1, W2, Bpack2);
  gemm1_256<<<MAXT256 * 16, 512, 98304, stream>>>(Apack, Bpack1, b1, hdr,
                                                  t256_e, t256_m, t256_s, Hpack);
  gemm2<<<71 * 8, 256, 0, stream>>>(Hpack, Bpack2, b2, hdr, tile_e, tile_m, sub0, perm, out);
}